// Round 4
// baseline (117.881 us; speedup 1.0000x reference)
//
#include <hip/hip_runtime.h>

#define QLEN 1024
#define KLEN 1024
#define BSZ 2
#define NHEAD 16
#define DHEAD 64
#define RS 2048            /* BSZ*NHEAD*DHEAD floats per seq row */
#define BLK_I 64
#define BLK_J 64
#define NJT (KLEN / BLK_J)

#define SC2f  0.18033688011112440f   /* 0.125 * log2(e) */
#define MBIGf 1.4426950408889634e30f /* 1e30 * log2(e)  */

typedef __attribute__((ext_vector_type(8))) short s16x8;
typedef __attribute__((ext_vector_type(4))) float f32x4;
typedef __attribute__((ext_vector_type(2))) float f32x2;

__device__ __forceinline__ unsigned short f2bf(float f) {
    union { float f; unsigned int u; } x; x.f = f;
    unsigned int r = x.u + 0x7fffu + ((x.u >> 16) & 1u);
    return (unsigned short)(r >> 16);
}

__global__ __launch_bounds__(256, 2)
void relattn_kernel(const float* __restrict__ q,
                    const float* __restrict__ kh,
                    const float* __restrict__ v,
                    const float* __restrict__ kr,
                    const float* __restrict__ segemb,
                    const float* __restrict__ segmat,
                    const float* __restrict__ rwb,
                    const float* __restrict__ rrb,
                    const float* __restrict__ rsb,
                    const float* __restrict__ mask,
                    float* __restrict__ out)
{
    // row stride 72 u16 = 144B = 9 granules (odd) -> granule-bank-group (row+g)%8
    __shared__ unsigned short KhL[BLK_J][72];
    __shared__ unsigned short KrL[BLK_J][72];
    __shared__ unsigned short VtL[DHEAD][72];   // [d][j], swizzle g_phys=(g+2(d&7))&7
    __shared__ unsigned short PlL[4][16][72];   // per-wave P tile 16x64
    __shared__ float SegF[BLK_I][67];           // fused ef*SC2 - MBIG*mask bias
    __shared__ float ef0s[BLK_I][2];

    // XCD swizzle: each XCD gets 64 consecutive logical blocks = 4 (b,n) pairs
    // x 16 i-tiles -> K/Kr/V working set ~4.2MB stays in its L2.
    const int F  = blockIdx.x;
    const int L  = (F & 7) * 64 + (F >> 3);
    const int i0 = (L & 15) * BLK_I;
    const int bn = L >> 4;
    const int b  = bn & 1;
    const int n  = bn >> 1;

    const int tid  = threadIdx.x;
    const int wave = tid >> 6;
    const int lane = tid & 63;
    const int q4   = lane >> 4;
    const int c    = lane & 15;
    const int boff = b * NHEAD * DHEAD + n * DHEAD;

    // ---- prologue: ef0[i][s] = sum_d (q + r_s_bias) * seg_embed[s] ----
    if (tid < 2 * BLK_I) {
        const int il = tid >> 1;
        const int s  = tid & 1;
        const float* qp2 = q + (size_t)(i0 + il) * RS + boff;
        const float* se  = segemb + (s * NHEAD + n) * DHEAD;
        const float* rs  = rsb + n * DHEAD;
        float a = 0.f;
#pragma unroll
        for (int dd = 0; dd < DHEAD; dd += 4) {
            const f32x4 qv = *(const f32x4*)(qp2 + dd);
            const f32x4 sv = *(const f32x4*)(se + dd);
            const f32x4 rv = *(const f32x4*)(rs + dd);
#pragma unroll
            for (int e = 0; e < 4; ++e) a += (qv[e] + rv[e]) * sv[e];
        }
        ef0s[il][s] = a;
    }

    // ---- Q fragments straight from global ----
    s16x8 qwf[2], qrf[2];
    {
        const float* qp = q + (size_t)(i0 + wave * 16 + c) * RS + boff;
#pragma unroll
        for (int kk = 0; kk < 2; ++kk) {
            const int off = kk * 32 + q4 * 8;
            const f32x4 q0 = *(const f32x4*)(qp + off);
            const f32x4 q1 = *(const f32x4*)(qp + off + 4);
            const f32x4 w0 = *(const f32x4*)(rwb + n * DHEAD + off);
            const f32x4 w1 = *(const f32x4*)(rwb + n * DHEAD + off + 4);
            const f32x4 r0 = *(const f32x4*)(rrb + n * DHEAD + off);
            const f32x4 r1 = *(const f32x4*)(rrb + n * DHEAD + off + 4);
            s16x8 tw, tr;
#pragma unroll
            for (int e = 0; e < 4; ++e) {
                tw[e]     = (short)f2bf(q0[e] + w0[e]);
                tw[4 + e] = (short)f2bf(q1[e] + w1[e]);
                tr[e]     = (short)f2bf(q0[e] + r0[e]);
                tr[4 + e] = (short)f2bf(q1[e] + r1[e]);
            }
            qwf[kk] = tw; qrf[kk] = tr;
        }
    }

    // ---- prefetch registers (single-buffered: consumed at loop top, refilled
    //      after B1 so global latency hides under compute) ----
    f32x4 ka[4], ra[4], mkv[4];
    float vv[16];
    f32x2 sg[16];
    const int sr   = tid >> 2;         // staging row (j-row for K, i-row for seg/mask)
    const int sc16 = (tid & 3) * 16;   // staging col base

    auto prefetch = [&](int jt) {
        const int j0 = jt * BLK_J;
        const float* khp = kh + (size_t)(j0 + sr) * RS + boff + sc16;
        const float* krp = kr + (size_t)(j0 + sr + 1) * RS + boff + sc16; // rel_shift +1
#pragma unroll
        for (int e = 0; e < 4; ++e) {
            ka[e] = *(const f32x4*)(khp + e * 4);
            ra[e] = *(const f32x4*)(krp + e * 4);
        }
        const float* vp = v + (size_t)(j0 + wave * 16) * RS + boff + lane;
#pragma unroll
        for (int jj = 0; jj < 16; ++jj) vv[jj] = vp[(size_t)jj * RS];
        const float* sp = segmat + (((size_t)(i0 + sr) * KLEN + (j0 + sc16)) * 2 + b) * 2;
#pragma unroll
        for (int e = 0; e < 16; ++e) sg[e] = *(const f32x2*)(sp + e * 4);
        const float* mp = mask + (size_t)(i0 + sr) * KLEN + j0 + sc16;
#pragma unroll
        for (int e = 0; e < 4; ++e) mkv[e] = *(const f32x4*)(mp + e * 4);
    };

    prefetch(0);
    __syncthreads();   // ef0s visible before first convert reads it

    int ig[4];
#pragma unroll
    for (int r = 0; r < 4; ++r) ig[r] = i0 + wave * 16 + q4 * 4 + r;

    float m[4], lsum[4];
    f32x4 acc[4];
#pragma unroll
    for (int r = 0; r < 4; ++r) { m[r] = -INFINITY; lsum[r] = 0.f; }
#pragma unroll
    for (int dt = 0; dt < 4; ++dt) acc[dt] = (f32x4)0.f;

    for (int jt = 0; jt < NJT; ++jt) {
        // ---- convert + write LDS (from prefetched regs) ----
        {
            s16x8 h0, h1, r0, r1;
#pragma unroll
            for (int e = 0; e < 4; ++e) {
                h0[e] = (short)f2bf(ka[0][e]); h0[4 + e] = (short)f2bf(ka[1][e]);
                h1[e] = (short)f2bf(ka[2][e]); h1[4 + e] = (short)f2bf(ka[3][e]);
                r0[e] = (short)f2bf(ra[0][e]); r0[4 + e] = (short)f2bf(ra[1][e]);
                r1[e] = (short)f2bf(ra[2][e]); r1[4 + e] = (short)f2bf(ra[3][e]);
            }
            *(s16x8*)&KhL[sr][sc16]     = h0;
            *(s16x8*)&KhL[sr][sc16 + 8] = h1;
            *(s16x8*)&KrL[sr][sc16]     = r0;
            *(s16x8*)&KrL[sr][sc16 + 8] = r1;
        }
#pragma unroll
        for (int gg = 0; gg < 2; ++gg) {
            s16x8 vb;
#pragma unroll
            for (int e = 0; e < 8; ++e) vb[e] = (short)f2bf(vv[gg * 8 + e]);
            const int pg = ((wave * 2 + gg) + 2 * (lane & 7)) & 7;  // bank-group (3d+g)%8
            *(s16x8*)&VtL[lane][pg * 8] = vb;
        }
        {
            const float e0v = ef0s[sr][0];
            const float e1v = ef0s[sr][1];
#pragma unroll
            for (int e = 0; e < 16; ++e)
                SegF[sr][sc16 + e] =
                    (sg[e][0] * e0v + sg[e][1] * e1v) * SC2f - MBIGf * mkv[e >> 2][e & 3];
        }
        __syncthreads();   // B1: tile visible

        if (jt + 1 < NJT) prefetch(jt + 1);   // flies under compute

        // ---- S = Qw*Kh^T + Qr*Kr^T ----
        f32x4 sj[4];
#pragma unroll
        for (int js = 0; js < 4; ++js) sj[js] = (f32x4)0.f;
#pragma unroll
        for (int kk = 0; kk < 2; ++kk) {
#pragma unroll
            for (int js = 0; js < 4; ++js) {
                const s16x8 khf = *(const s16x8*)&KhL[js * 16 + c][kk * 32 + q4 * 8];
                const s16x8 krf = *(const s16x8*)&KrL[js * 16 + c][kk * 32 + q4 * 8];
                sj[js] = __builtin_amdgcn_mfma_f32_16x16x32_bf16(qwf[kk], khf, sj[js], 0, 0, 0);
                sj[js] = __builtin_amdgcn_mfma_f32_16x16x32_bf16(qrf[kk], krf, sj[js], 0, 0, 0);
            }
        }

        // ---- bias + online softmax (log2 domain) ----
        float mt[4];
#pragma unroll
        for (int r = 0; r < 4; ++r) {
            const int iloc = wave * 16 + q4 * 4 + r;   // block-local i row (FIX: + wave*16)
#pragma unroll
            for (int js = 0; js < 4; ++js)
                sj[js][r] = sj[js][r] * SC2f + SegF[iloc][js * 16 + c];
            mt[r] = fmaxf(fmaxf(sj[0][r], sj[1][r]), fmaxf(sj[2][r], sj[3][r]));
        }
#pragma unroll
        for (int xm = 1; xm <= 8; xm <<= 1) {
#pragma unroll
            for (int r = 0; r < 4; ++r)
                mt[r] = fmaxf(mt[r], __shfl_xor(mt[r], xm, 64));
        }
#pragma unroll
        for (int r = 0; r < 4; ++r) {
            const float mn  = fmaxf(m[r], mt[r]);
            const float scl = __builtin_amdgcn_exp2f(m[r] - mn);
            m[r] = mn;
#pragma unroll
            for (int dt = 0; dt < 4; ++dt) acc[dt][r] *= scl;
            float ps = 0.f;
#pragma unroll
            for (int js = 0; js < 4; ++js) {
                const float p = __builtin_amdgcn_exp2f(sj[js][r] - mn);
                ps += p;
                PlL[wave][q4 * 4 + r][js * 16 + c] = f2bf(p);
            }
#pragma unroll
            for (int xm = 1; xm <= 8; xm <<= 1) ps += __shfl_xor(ps, xm, 64);
            lsum[r] = lsum[r] * scl + ps;
        }

        // ---- PV: acc += P(16x64) * V(64x64) ----
#pragma unroll
        for (int kk = 0; kk < 2; ++kk) {
            const s16x8 pf = *(const s16x8*)&PlL[wave][c][kk * 32 + q4 * 8];
#pragma unroll
            for (int dt = 0; dt < 4; ++dt) {
                const s16x8 vf = *(const s16x8*)&VtL[dt * 16 + c]
                                   [((kk * 4 + q4 + 2 * (c & 7)) & 7) * 8];
                acc[dt] = __builtin_amdgcn_mfma_f32_16x16x32_bf16(pf, vf, acc[dt], 0, 0, 0);
            }
        }
        __syncthreads();   // B0: everyone done reading tile jt
    }

    // ---- epilogue: normalize and store ----
#pragma unroll
    for (int r = 0; r < 4; ++r) {
        const float inv = 1.f / lsum[r];
        float* op = out + (size_t)ig[r] * RS + boff;
#pragma unroll
        for (int dt = 0; dt < 4; ++dt)
            op[dt * 16 + c] = acc[dt][r] * inv;
    }
}

extern "C" void kernel_launch(void* const* d_in, const int* in_sizes, int n_in,
                              void* d_out, int out_size, void* d_ws, size_t ws_size,
                              hipStream_t stream) {
    const float* q   = (const float*)d_in[0];
    const float* kh  = (const float*)d_in[1];
    const float* v   = (const float*)d_in[2];
    const float* kr  = (const float*)d_in[3];
    const float* se  = (const float*)d_in[4];
    const float* sm  = (const float*)d_in[5];
    const float* rwb = (const float*)d_in[6];
    const float* rrb = (const float*)d_in[7];
    const float* rsb = (const float*)d_in[8];
    const float* msk = (const float*)d_in[9];
    float* out = (float*)d_out;
    const int nblk = (QLEN / BLK_I) * BSZ * NHEAD;   // 512
    relattn_kernel<<<nblk, 256, 0, stream>>>(q, kh, v, kr, se, sm, rwb, rrb, rsb, msk, out);
}

// Round 5
// 76.984 us; speedup vs baseline: 1.5312x; 1.5312x over previous
//
#include <hip/hip_runtime.h>

#define QLEN 1024
#define KLEN 1024
#define BSZ 2
#define NHEAD 16
#define DHEAD 64
#define RS 2048            /* BSZ*NHEAD*DHEAD floats per seq row */
#define BLK_I 64
#define BLK_J 64
#define NJT (KLEN / BLK_J)

#define SC2f  0.18033688011112440f   /* 0.125 * log2(e) */
#define MBIGf 1.4426950408889634e30f /* 1e30 * log2(e)  */

typedef __attribute__((ext_vector_type(8))) short s16x8;
typedef __attribute__((ext_vector_type(4))) float f32x4;
typedef __attribute__((ext_vector_type(2))) float f32x2;

__device__ __forceinline__ unsigned short f2bf(float f) {
    union { float f; unsigned int u; } x; x.f = f;
    unsigned int r = x.u + 0x7fffu + ((x.u >> 16) & 1u);
    return (unsigned short)(r >> 16);
}

__global__ __launch_bounds__(256, 2)
void relattn_kernel(const float* __restrict__ q,
                    const float* __restrict__ kh,
                    const float* __restrict__ v,
                    const float* __restrict__ kr,
                    const float* __restrict__ segemb,
                    const float* __restrict__ segmat,
                    const float* __restrict__ rwb,
                    const float* __restrict__ rrb,
                    const float* __restrict__ rsb,
                    const float* __restrict__ mask,
                    float* __restrict__ out)
{
    // 72-u16 rows (144B = 9 granules, odd) -> b128 reads/writes at baseline
    // conflict level; V uses bijective granule swizzle (g + 2(d&7)) & 7.
    __shared__ unsigned short KhL[2][BLK_J][72];
    __shared__ unsigned short KrL[2][BLK_J][72];
    __shared__ unsigned short VtL[2][DHEAD][72];
    __shared__ unsigned short PlL[4][16][72];   // per-wave P tile (no barrier needed)
    __shared__ float ef0s[BLK_I][2];

    const int i0 = blockIdx.x * BLK_I;   // natural order: i-tile fastest ->
    const int b  = blockIdx.y;           // i-tiles of one (b,n) spread across XCDs,
    const int n  = blockIdx.z;           // preserving segmat L2/L3 locality (r1: 115MB)

    const int tid  = threadIdx.x;
    const int wave = tid >> 6;
    const int lane = tid & 63;
    const int q4   = lane >> 4;
    const int c    = lane & 15;
    const int boff = b * NHEAD * DHEAD + n * DHEAD;

    // ---- prologue: ef0[i][s] = sum_d (q + r_s_bias) * seg_embed[s] ----
    if (tid < 2 * BLK_I) {
        const int il = tid >> 1;
        const int s  = tid & 1;
        const float* qp2 = q + (size_t)(i0 + il) * RS + boff;
        const float* se  = segemb + (s * NHEAD + n) * DHEAD;
        const float* rs  = rsb + n * DHEAD;
        float a = 0.f;
#pragma unroll
        for (int dd = 0; dd < DHEAD; dd += 4) {
            const f32x4 qv = *(const f32x4*)(qp2 + dd);
            const f32x4 sv = *(const f32x4*)(se + dd);
            const f32x4 rv = *(const f32x4*)(rs + dd);
#pragma unroll
            for (int e = 0; e < 4; ++e) a += (qv[e] + rv[e]) * sv[e];
        }
        ef0s[il][s] = a;
    }

    // ---- Q fragments straight from global ----
    s16x8 qwf[2], qrf[2];
    {
        const float* qp = q + (size_t)(i0 + wave * 16 + c) * RS + boff;
#pragma unroll
        for (int kk = 0; kk < 2; ++kk) {
            const int off = kk * 32 + q4 * 8;
            const f32x4 q0 = *(const f32x4*)(qp + off);
            const f32x4 q1 = *(const f32x4*)(qp + off + 4);
            const f32x4 w0 = *(const f32x4*)(rwb + n * DHEAD + off);
            const f32x4 w1 = *(const f32x4*)(rwb + n * DHEAD + off + 4);
            const f32x4 r0 = *(const f32x4*)(rrb + n * DHEAD + off);
            const f32x4 r1 = *(const f32x4*)(rrb + n * DHEAD + off + 4);
            s16x8 tw, tr;
#pragma unroll
            for (int e = 0; e < 4; ++e) {
                tw[e]     = (short)f2bf(q0[e] + w0[e]);
                tw[4 + e] = (short)f2bf(q1[e] + w1[e]);
                tr[e]     = (short)f2bf(q0[e] + r0[e]);
                tr[4 + e] = (short)f2bf(q1[e] + r1[e]);
            }
            qwf[kk] = tw; qrf[kk] = tr;
        }
    }

    int ig[4];
#pragma unroll
    for (int r = 0; r < 4; ++r) ig[r] = i0 + wave * 16 + q4 * 4 + r;

    // ---- staging state (short-liveness: issue -> write within one jt) ----
    f32x4 ka[4], ra[4];
    float vv[16];
    f32x2 smv[16];
    f32x4 mkv[4];
    const int sr   = tid >> 2;         // staging row
    const int sc16 = (tid & 3) * 16;   // staging col base

    auto issueSeg = [&](int jt) {
        const int j0 = jt * BLK_J;
#pragma unroll
        for (int r = 0; r < 4; ++r) {
#pragma unroll
            for (int js = 0; js < 4; ++js) {
                const size_t sij = (size_t)ig[r] * KLEN + (j0 + js * 16 + c);
                smv[r * 4 + js] = *(const f32x2*)(segmat + (sij * 2 + b) * 2);
            }
            f32x4 t;
#pragma unroll
            for (int js = 0; js < 4; ++js)
                t[js] = mask[(size_t)ig[r] * KLEN + (j0 + js * 16 + c)];
            mkv[r] = t;
        }
    };

    auto issueKV = [&](int jt) {
        const int j0 = jt * BLK_J;
        const float* khp = kh + (size_t)(j0 + sr) * RS + boff + sc16;
        const float* krp = kr + (size_t)(j0 + sr + 1) * RS + boff + sc16; // rel_shift +1
#pragma unroll
        for (int e = 0; e < 4; ++e) {
            ka[e] = *(const f32x4*)(khp + e * 4);
            ra[e] = *(const f32x4*)(krp + e * 4);
        }
        const float* vp = v + (size_t)(j0 + wave * 16) * RS + boff + lane;
#pragma unroll
        for (int jj = 0; jj < 16; ++jj) vv[jj] = vp[(size_t)jj * RS];
    };

    auto writeKV = [&](int buf) {
        s16x8 h0, h1, r0, r1;
#pragma unroll
        for (int e = 0; e < 4; ++e) {
            h0[e] = (short)f2bf(ka[0][e]); h0[4 + e] = (short)f2bf(ka[1][e]);
            h1[e] = (short)f2bf(ka[2][e]); h1[4 + e] = (short)f2bf(ka[3][e]);
            r0[e] = (short)f2bf(ra[0][e]); r0[4 + e] = (short)f2bf(ra[1][e]);
            r1[e] = (short)f2bf(ra[2][e]); r1[4 + e] = (short)f2bf(ra[3][e]);
        }
        *(s16x8*)&KhL[buf][sr][sc16]     = h0;
        *(s16x8*)&KhL[buf][sr][sc16 + 8] = h1;
        *(s16x8*)&KrL[buf][sr][sc16]     = r0;
        *(s16x8*)&KrL[buf][sr][sc16 + 8] = r1;
#pragma unroll
        for (int gg = 0; gg < 2; ++gg) {
            s16x8 vb;
#pragma unroll
            for (int e = 0; e < 8; ++e) vb[e] = (short)f2bf(vv[gg * 8 + e]);
            const int pg = ((wave * 2 + gg) + 2 * (lane & 7)) & 7;  // bijective swizzle
            *(s16x8*)&VtL[buf][lane][pg * 8] = vb;
        }
    };

    // ---- stage tile 0 ----
    issueKV(0);
    writeKV(0);
    __syncthreads();   // buf0 + ef0s visible

    float e0[4], e1[4];
#pragma unroll
    for (int r = 0; r < 4; ++r) {
        const int iloc = wave * 16 + q4 * 4 + r;
        e0[r] = ef0s[iloc][0];
        e1[r] = ef0s[iloc][1];
    }

    float m[4], lsum[4];
    f32x4 acc[4];
#pragma unroll
    for (int r = 0; r < 4; ++r) { m[r] = -INFINITY; lsum[r] = 0.f; }
#pragma unroll
    for (int dt = 0; dt < 4; ++dt) acc[dt] = (f32x4)0.f;

    int cur = 0;
    for (int jt = 0; jt < NJT; ++jt) {
        const int jn = (jt + 1 < NJT) ? jt + 1 : jt;   // clamp (select, no branch)

        // ---- issue next-tile loads; pin them here (single BB => scheduler
        //      can't sink past sched_barrier) ----
        issueSeg(jt);
        issueKV(jn);
        __builtin_amdgcn_sched_barrier(0);

        // ---- S = Qw*Kh^T + Qr*Kr^T from buf[cur] ----
        f32x4 sj[4];
#pragma unroll
        for (int js = 0; js < 4; ++js) sj[js] = (f32x4)0.f;
#pragma unroll
        for (int kk = 0; kk < 2; ++kk) {
#pragma unroll
            for (int js = 0; js < 4; ++js) {
                const s16x8 khf = *(const s16x8*)&KhL[cur][js * 16 + c][kk * 32 + q4 * 8];
                const s16x8 krf = *(const s16x8*)&KrL[cur][js * 16 + c][kk * 32 + q4 * 8];
                sj[js] = __builtin_amdgcn_mfma_f32_16x16x32_bf16(qwf[kk], khf, sj[js], 0, 0, 0);
                sj[js] = __builtin_amdgcn_mfma_f32_16x16x32_bf16(qrf[kk], krf, sj[js], 0, 0, 0);
            }
        }

        // ---- bias + online softmax (log2 domain); seg wait lands here ----
        float mt[4];
#pragma unroll
        for (int r = 0; r < 4; ++r) {
#pragma unroll
            for (int js = 0; js < 4; ++js) {
                const f32x2 sm = smv[r * 4 + js];
                sj[js][r] = sj[js][r] * SC2f + (sm[0] * e0[r] + sm[1] * e1[r]) * SC2f
                            - MBIGf * mkv[r][js];
            }
            mt[r] = fmaxf(fmaxf(sj[0][r], sj[1][r]), fmaxf(sj[2][r], sj[3][r]));
        }
#pragma unroll
        for (int xm = 1; xm <= 8; xm <<= 1) {
#pragma unroll
            for (int r = 0; r < 4; ++r)
                mt[r] = fmaxf(mt[r], __shfl_xor(mt[r], xm, 64));
        }
#pragma unroll
        for (int r = 0; r < 4; ++r) {
            const float mn  = fmaxf(m[r], mt[r]);
            const float scl = __builtin_amdgcn_exp2f(m[r] - mn);
            m[r] = mn;
#pragma unroll
            for (int dt = 0; dt < 4; ++dt) acc[dt][r] *= scl;
            float ps = 0.f;
#pragma unroll
            for (int js = 0; js < 4; ++js) {
                const float p = __builtin_amdgcn_exp2f(sj[js][r] - mn);
                ps += p;
                PlL[wave][q4 * 4 + r][js * 16 + c] = f2bf(p);
            }
            lsum[r] = lsum[r] * scl + ps;   // per-lane partial; reduced at epilogue
        }

        // ---- write next buffer (K/V vmcnt wait lands here, ~QK+softmax later) ----
        writeKV(cur ^ 1);

        // ---- PV: acc += P(16x64) * V(64x64) from buf[cur] ----
#pragma unroll
        for (int kk = 0; kk < 2; ++kk) {
            const s16x8 pf = *(const s16x8*)&PlL[wave][c][kk * 32 + q4 * 8];
#pragma unroll
            for (int dt = 0; dt < 4; ++dt) {
                const s16x8 vf = *(const s16x8*)&VtL[cur][dt * 16 + c]
                                   [((kk * 4 + q4 + 2 * (c & 7)) & 7) * 8];
                acc[dt] = __builtin_amdgcn_mfma_f32_16x16x32_bf16(pf, vf, acc[dt], 0, 0, 0);
            }
        }

        __syncthreads();   // readers of buf[cur] done; buf[cur^1] visible
        cur ^= 1;
    }

    // ---- epilogue: reduce lsum across the 16 c-lanes, normalize, store ----
#pragma unroll
    for (int xm = 1; xm <= 8; xm <<= 1) {
#pragma unroll
        for (int r = 0; r < 4; ++r) lsum[r] += __shfl_xor(lsum[r], xm, 64);
    }
#pragma unroll
    for (int r = 0; r < 4; ++r) {
        const float inv = 1.f / lsum[r];
        float* op = out + (size_t)ig[r] * RS + boff;
#pragma unroll
        for (int dt = 0; dt < 4; ++dt)
            op[dt * 16 + c] = acc[dt][r] * inv;
    }
}

extern "C" void kernel_launch(void* const* d_in, const int* in_sizes, int n_in,
                              void* d_out, int out_size, void* d_ws, size_t ws_size,
                              hipStream_t stream) {
    const float* q   = (const float*)d_in[0];
    const float* kh  = (const float*)d_in[1];
    const float* v   = (const float*)d_in[2];
    const float* kr  = (const float*)d_in[3];
    const float* se  = (const float*)d_in[4];
    const float* sm  = (const float*)d_in[5];
    const float* rwb = (const float*)d_in[6];
    const float* rrb = (const float*)d_in[7];
    const float* rsb = (const float*)d_in[8];
    const float* msk = (const float*)d_in[9];
    float* out = (float*)d_out;
    dim3 grid(QLEN / BLK_I, BSZ, NHEAD);   // 16 x 2 x 16 = 512 blocks
    relattn_kernel<<<grid, 256, 0, stream>>>(q, kh, v, kr, se, sm, rwb, rrb, rsb, msk, out);
}